// Round 1
// baseline (346.179 us; speedup 1.0000x reference)
//
#include <hip/hip_runtime.h>
#include <stdint.h>

#define UU 512
#define NHEAD 8
#define CHK 64
#define NB 8
#define NXX 1024
#define NYY 1024
#define SCALE_F 0.125f   // 1/sqrt(64)

typedef __bf16 bf16x8 __attribute__((ext_vector_type(8)));
typedef float f32x4 __attribute__((ext_vector_type(4)));
typedef unsigned short us4 __attribute__((ext_vector_type(4)));

__device__ __forceinline__ unsigned short f2bf(float f) {
  union { float f; uint32_t u; } v; v.f = f;
  return (unsigned short)((v.u + 0x7FFFu + ((v.u >> 16) & 1u)) >> 16);
}

// ---------------------------------------------------------------------------
// Mask dtype probe: u8 bool -> nonzero bytes at p%4==1; f32 1.0f -> nonzero at
// p%4==3 only; int32 0/1 -> neither. det[0]: any nonzero @1, det[1]: any @3.
__global__ void detect_mask(const unsigned char* __restrict__ m, int* __restrict__ det) {
  int t = threadIdx.x;
  int c1 = 0, c3 = 0;
  for (int q = t; q < 16384; q += 256) {   // first 65536 bytes (always in-bounds)
    c1 |= m[q * 4 + 1];
    c3 |= m[q * 4 + 3];
  }
  if (c1) atomicOr(&det[0], 1);
  if (c3) atomicOr(&det[1], 1);
}

// ---------------------------------------------------------------------------
__global__ void cast_w(const float* __restrict__ W, unsigned short* __restrict__ Wb) {
  int i = blockIdx.x * 256 + threadIdx.x;  // grid covers 512*512 exactly
  Wb[i] = f2bf(W[i]);
}

// ---------------------------------------------------------------------------
// xt[bz][n][i] (bf16) = src[b][i][n],  bz = which*8 + b  (which: 0=x, 1=y)
__global__ __launch_bounds__(256) void transpose_cast(
    const float* __restrict__ x, const float* __restrict__ y,
    unsigned short* __restrict__ tr) {
  __shared__ float tile[64][65];
  int nt = blockIdx.x, it = blockIdx.y, bz = blockIdx.z;
  int b = bz & 7;
  const float* src = (bz >> 3) ? y : x;
  int t = threadIdx.x;
  int col = t & 63, row4 = t >> 6;
  const float* base = src + ((size_t)b * UU + it * 64) * NXX + nt * 64;
#pragma unroll
  for (int r = 0; r < 16; r++) {
    int i = row4 + r * 4;
    tile[i][col] = base[(size_t)i * NXX + col];
  }
  __syncthreads();
  unsigned short* ob = tr + ((size_t)bz * NXX + nt * 64) * UU + it * 64;
#pragma unroll
  for (int r = 0; r < 16; r++) {
    int n = row4 + r * 4;
    ob[(size_t)n * UU + col] = f2bf(tile[col][n]);  // stride-65 read: conflict-free
  }
}

// ---------------------------------------------------------------------------
// cv[bz][n][u] = sum_i W[u][i] * xt[bz][n][i]   (i.e. _x^T, per batch/which)
// M=u, N=n, K=512. A frag = W rows (contig K), B frag = xt rows (contig K).
__global__ __launch_bounds__(256) void conv_gemm(
    const unsigned short* __restrict__ tr, const unsigned short* __restrict__ Wb,
    unsigned short* __restrict__ cv) {
  int nt = blockIdx.x, ut = blockIdx.y, bz = blockIdx.z;
  int t = threadIdx.x;
  int w = t >> 6, l = t & 63;
  int lane_m = l & 15, lane_g = l >> 4;
  int n0 = nt * 64, u0 = ut * 64 + w * 16;
  const unsigned short* xbase = tr + (size_t)bz * NXX * UU;
  f32x4 acc[4] = {};
  for (int kb = 0; kb < 16; kb++) {
    int k = kb * 32 + lane_g * 8;
    bf16x8 a = *(const bf16x8*)(Wb + (size_t)(u0 + lane_m) * UU + k);
#pragma unroll
    for (int tn = 0; tn < 4; tn++) {
      bf16x8 bf = *(const bf16x8*)(xbase + (size_t)(n0 + tn * 16 + lane_m) * UU + k);
      acc[tn] = __builtin_amdgcn_mfma_f32_16x16x32_bf16(a, bf, acc[tn], 0, 0, 0);
    }
  }
  // C/D: col(lane&15)=n, row(4*(lane>>4)+r)=u  -> 4 consecutive u per lane: 8B store
  unsigned short* ob = cv + (size_t)bz * NXX * UU;
#pragma unroll
  for (int tn = 0; tn < 4; tn++) {
    int n = n0 + tn * 16 + lane_m;
    int u = u0 + 4 * lane_g;
    us4 pk;
    pk.x = f2bf(acc[tn][0]); pk.y = f2bf(acc[tn][1]);
    pk.z = f2bf(acc[tn][2]); pk.w = f2bf(acc[tn][3]);
    *(us4*)(ob + (size_t)n * UU + u) = pk;
  }
}

// ---------------------------------------------------------------------------
// Per (b, 64x64 n/m tile): S[n][m] per head via MFMA (K=64), fused
// relu * mask accumulate -> atomicAdd sim[b][h]; mask count -> cnt[b].
__global__ __launch_bounds__(256) void score_kernel(
    const unsigned short* __restrict__ cv, const void* __restrict__ maskp,
    const int* __restrict__ det, float* __restrict__ sim,
    unsigned int* __restrict__ cnt) {
  __shared__ float mf[64][68];  // pad: 4-row advance = 16 banks -> conflict-free
  int ntb = blockIdx.x, mtb = blockIdx.y, b = blockIdx.z;
  int t = threadIdx.x, w = t >> 6, l = t & 63;
  int lane_m = l & 15, lane_g = l >> 4;
  int n0 = ntb * 64, m0 = mtb * 64;

  int mode = det[0] ? 0 : (det[1] ? 2 : 1);  // 0=u8, 1=i32, 2=f32 (uniform)
  unsigned int c = 0;
  size_t mbase = ((size_t)b * NXX + n0) * NYY + m0;
  int col = t & 63, row4 = t >> 6;
#pragma unroll
  for (int r = 0; r < 16; r++) {
    int row = row4 + r * 4;
    size_t idx = mbase + (size_t)row * NYY + col;
    int v;
    if (mode == 0)      v = ((const unsigned char*)maskp)[idx] != 0;
    else if (mode == 1) v = ((const int*)maskp)[idx] != 0;
    else                v = ((const float*)maskp)[idx] != 0.0f;
    mf[row][col] = (float)v;
    c += (unsigned)v;
  }
  for (int s = 1; s < 64; s <<= 1) c += __shfl_xor(c, s);
  if (l == 0) atomicAdd(&cnt[b], c);
  __syncthreads();

  const unsigned short* xb = cv + ((size_t)b * NXX + n0) * UU;           // x side
  const unsigned short* yb = cv + ((size_t)(NB + b) * NYY + m0) * UU;    // y side
#pragma unroll
  for (int hh = 0; hh < 2; hh++) {
    int h = w * 2 + hh;
    int co = h * CHK;
    bf16x8 afr[4][2], bfr[4][2];
#pragma unroll
    for (int tt = 0; tt < 4; tt++)
#pragma unroll
      for (int kb = 0; kb < 2; kb++) {
        afr[tt][kb] = *(const bf16x8*)(xb + (size_t)(tt * 16 + lane_m) * UU + co + kb * 32 + lane_g * 8);
        bfr[tt][kb] = *(const bf16x8*)(yb + (size_t)(tt * 16 + lane_m) * UU + co + kb * 32 + lane_g * 8);
      }
    float hsum = 0.f;
#pragma unroll
    for (int tn = 0; tn < 4; tn++)
#pragma unroll
      for (int tm = 0; tm < 4; tm++) {
        f32x4 acc = {};
        acc = __builtin_amdgcn_mfma_f32_16x16x32_bf16(afr[tn][0], bfr[tm][0], acc, 0, 0, 0);
        acc = __builtin_amdgcn_mfma_f32_16x16x32_bf16(afr[tn][1], bfr[tm][1], acc, 0, 0, 0);
#pragma unroll
        for (int r = 0; r < 4; r++) {
          int nl = tn * 16 + 4 * lane_g + r;
          int ml = tm * 16 + lane_m;
          float v = acc[r];
          v = v > 0.f ? v : 0.f;
          hsum += v * mf[nl][ml];
        }
      }
    for (int s = 1; s < 64; s <<= 1) hsum += __shfl_xor(hsum, s);
    if (l == 0) atomicAdd(&sim[b * NHEAD + h], hsum);
  }
}

// ---------------------------------------------------------------------------
__global__ void finalize(const float* __restrict__ sim, const unsigned int* __restrict__ cnt,
                         const float* __restrict__ fcw, const float* __restrict__ fcb,
                         float* __restrict__ out) {
  int b = threadIdx.x;
  if (b < NB) {
    float s = 0.f;
#pragma unroll
    for (int h = 0; h < NHEAD; h++) s += sim[b * NHEAD + h] * fcw[h];
    unsigned int n = cnt[b];
    if (n == 0) n = 1;
    out[b] = s * (SCALE_F / (float)n) + fcb[0];
  }
}

// ---------------------------------------------------------------------------
extern "C" void kernel_launch(void* const* d_in, const int* in_sizes, int n_in,
                              void* d_out, int out_size, void* d_ws, size_t ws_size,
                              hipStream_t stream) {
  const float* x = (const float*)d_in[0];
  const float* y = (const float*)d_in[1];
  const void* mask = d_in[2];
  const float* W = (const float*)d_in[3];
  const float* fcw = (const float*)d_in[4];
  const float* fcb = (const float*)d_in[5];
  float* out = (float*)d_out;
  char* ws = (char*)d_ws;

  // ws layout: [0,16M): transposed inputs bf16 [2*B][1024][512]
  //            [16M,32M): conv outputs bf16 [2*B][1024][512]
  //            [32M,+512K): W bf16 ; then stats (sim[64]f32, cnt[8]u32, det[2]i32)
  unsigned short* tr = (unsigned short*)ws;
  unsigned short* cv = (unsigned short*)(ws + (16u << 20));
  unsigned short* Wb = (unsigned short*)(ws + (32u << 20));
  char* st = ws + (32u << 20) + (1u << 19);
  float* sim = (float*)st;
  unsigned int* cnt = (unsigned int*)(st + 256);
  int* det = (int*)(st + 288);

  hipMemsetAsync(st, 0, 512, stream);
  detect_mask<<<1, 256, 0, stream>>>((const unsigned char*)mask, det);
  cast_w<<<1024, 256, 0, stream>>>(W, Wb);
  transpose_cast<<<dim3(16, 8, 16), 256, 0, stream>>>(x, y, tr);
  conv_gemm<<<dim3(16, 8, 16), 256, 0, stream>>>(tr, Wb, cv);
  score_kernel<<<dim3(16, 16, 8), 256, 0, stream>>>(cv, mask, det, sim, cnt);
  finalize<<<1, 64, 0, stream>>>(sim, cnt, fcw, fcb, out);
}